// Round 6
// baseline (172.785 us; speedup 1.0000x reference)
//
#include <hip/hip_runtime.h>
#include <math.h>

#define N_    32
#define CIN   128
#define H_    56
#define W_    56
#define COUT  256
#define OH    28
#define OW    28
#define M_    (N_ * OH * OW)      // 25088
#define OUTSZ (M_ * COUT)         // 6,422,528
#define EPS_  0.007f

typedef unsigned short U16;
typedef float f32x4  __attribute__((ext_vector_type(4)));
typedef short bf16x8 __attribute__((ext_vector_type(8)));

// ws float-region layout
#define SCALE_IDX 0
#define ZERO_IDX  8             // wsf[8..15]: 32B zero page for OOB global_load_lds
#define WSQ_IDX   16            // 256 floats
#define PSQ_IDX   512           // 25088 floats
#define U16_BYTE_OFF 102400     // = 25600 floats, 256B aligned

__device__ __forceinline__ U16 f2bf(float f) {
    unsigned int u = __builtin_bit_cast(unsigned int, f);
    u = (u + 0x7fffu + ((u >> 16) & 1u)) >> 16;   // RNE
    return (U16)u;
}
__device__ __forceinline__ float b2f(U16 h) {
    unsigned int u = ((unsigned int)h) << 16;
    return __builtin_bit_cast(float, u);
}

__device__ __forceinline__ void gl_lds16(const U16* g, U16* l) {
    __builtin_amdgcn_global_load_lds((const __attribute__((address_space(1))) void*)g,
                                     (__attribute__((address_space(3))) void*)l, 16, 0, 0);
}

// ---------------- fused prep: x transpose + weight reorder + wsq/scale/zero ----------------
__global__ void k_prep(const float* __restrict__ x,
                       const float* __restrict__ w_yat,
                       const float* __restrict__ w_lin,
                       const float* __restrict__ w_short,
                       const float* __restrict__ alpha,
                       U16* __restrict__ xt, U16* __restrict__ B1,
                       U16* __restrict__ B3, U16* __restrict__ B2,
                       float* __restrict__ wsf) {
    int b = blockIdx.x, t = threadIdx.x;
    if (b < 6272) {
        int idx = b * 256 + t;                     // 1,605,632 exactly
        int ci8 = idx & 15;
        int px  = idx >> 4;                        // n*3136 + hw
        int n   = px / 3136;
        int hw  = px - n * 3136;
        const float* src = x + ((size_t)n * 128 + ci8 * 8) * 3136 + hw;
        unsigned int o[4];
#pragma unroll
        for (int j = 0; j < 4; ++j) {
            float a = src[(size_t)(2 * j)     * 3136];
            float c = src[(size_t)(2 * j + 1) * 3136];
            o[j] = (unsigned)f2bf(a) | ((unsigned)f2bf(c) << 16);
        }
        *(uint4*)&xt[(size_t)px * 128 + ci8 * 8] = *(const uint4*)o;
    } else if (b < 9856) {
        int idx = (b - 6272) * 256 + t;            // 917,504 exactly
        if (idx < 294912) {
            int co = idx / 1152, k = idx % 1152;
            int khkw = k >> 7, ci = k & 127;
            B1[idx] = f2bf(w_yat[(co * 128 + ci) * 9 + khkw]);
        } else if (idx < 294912 + 589824) {
            int i2 = idx - 294912;
            int co = i2 / 2304, k = i2 % 2304;
            int khkw = k >> 8, cy = k & 255;
            B3[i2] = f2bf(w_lin[(co * 256 + cy) * 9 + khkw]);
        } else {
            int i3 = idx - (294912 + 589824);      // < 32768
            B2[i3] = f2bf(w_short[i3]);
        }
    } else {
        int co = b - 9856, lane = t & 63, wv = t >> 6;
        const float* wc = w_yat + (size_t)co * 1152;
        float s = 0.f;
        for (int i = t; i < 1152; i += 256) { float v = wc[i]; s += v * v; }
#pragma unroll
        for (int off = 32; off >= 1; off >>= 1) s += __shfl_xor(s, off);
        __shared__ float red[4];
        if (lane == 0) red[wv] = s;
        __syncthreads();
        if (t == 0) {
            wsf[WSQ_IDX + co] = red[0] + red[1] + red[2] + red[3];
            if (co == 0) wsf[SCALE_IDX] = powf(16.0f / log1pf(256.0f), alpha[0]);
        }
        if (co == 0 && t >= 8 && t < 16) wsf[ZERO_IDX + (t - 8)] = 0.f;
    }
}

// ---------------- per-patch squared norm: one wave per output pixel ----------------
__global__ void k_psq(const U16* __restrict__ xt, float* __restrict__ wsf) {
    int t = threadIdx.x, lane = t & 63, wv = t >> 6;
    int gm = blockIdx.x * 4 + wv;                  // < 25088 exactly
    int ow = gm % 28, tt = gm / 28;
    int oh = tt % 28, n = tt / 28;
    const U16* xb = xt + (size_t)n * 56 * 56 * 128;
    float s = 0.f;
#pragma unroll
    for (int kh = 0; kh < 3; ++kh) {
        int ih = oh * 2 - 1 + kh;
        if ((unsigned)ih >= 56) continue;
#pragma unroll
        for (int kw = 0; kw < 3; ++kw) {
            int iw = ow * 2 - 1 + kw;
            if ((unsigned)iw >= 56) continue;
            unsigned int v = *(const unsigned int*)&xb[(size_t)((ih * 56 + iw) << 7) + lane * 2];
            float f0 = b2f((U16)(v & 0xffff)), f1 = b2f((U16)(v >> 16));
            s += f0 * f0 + f1 * f1;
        }
    }
#pragma unroll
    for (int off = 32; off >= 1; off >>= 1) s += __shfl_xor(s, off);
    if (lane == 0) wsf[PSQ_IDX + gm] = s;
}

// ---------------- MFMA implicit-GEMM, BM=128 BN=64 BK=64, single-buffered (m97 structure) ----
// 25 KB LDS -> 4 blocks/CU co-resident (implicit wave-level overlap hides staging latency).
// XCD-aware bijective swizzle: logical = (bid&7)*98 + (bid>>3)  (grid%8==0).
// MODE 0: yat dot conv (3x3 s2 p1 over xt) -> ybuf bf16; fused 1x1 s2 shortcut -> out (f32 NCHW)
// MODE 3: lin 3x3 s1 p1 over ybuf, split-K=2: bid>=784 is split 1; writes bf16 partial (NCHW)
template<int KTOT, int MODE>
__launch_bounds__(256, 4)
__global__ void k_gemm(const U16* __restrict__ Asrc, const U16* __restrict__ Bp,
                       const U16* __restrict__ B2p,
                       const float* __restrict__ wsf, U16* __restrict__ ybuf,
                       float* __restrict__ out) {
    __shared__ U16 Ab[128 * 64];                   // 16 KB
    __shared__ U16 Bb[64 * 64];                    // 8 KB
    __shared__ float psq_s[128];
    __shared__ float wsq_s[64];

    int t = threadIdx.x, lane = t & 63, wv = t >> 6;
    int wr = wv >> 1, wc = wv & 1;                 // wave tile: rows wr*64 (4 frags), cols wc*32 (2 frags)
    int bid = blockIdx.x;
    int s = 0, inner = bid;
    if (MODE == 3) { s = (bid >= 784) ? 1 : 0; inner = bid - 784 * s; }
    int logical = (inner & 7) * 98 + (inner >> 3); // XCD swizzle (784 = 8*98, bijective)
    int m0 = (logical >> 2) * 128;
    int co_base = (logical & 3) * 64;

    if (MODE == 0) {
        if (t < 128)       psq_s[t] = wsf[PSQ_IDX + m0 + t];
        else if (t < 192)  wsq_s[t - 128] = wsf[WSQ_IDX + co_base + (t - 128)];
    }

    const U16* zptr = (const U16*)&wsf[ZERO_IDX];

    // A-staging: thread t stages rows r0+32*rr (rr=0..3), 16B each; LDS dest linear in t
    int r0 = t >> 3, phys = t & 7;
    int aplog = phys ^ (r0 & 7);                   // (r0+32*rr)&7 == r0&7
    int an[4], aoh[4], aow[4];
#pragma unroll
    for (int rr = 0; rr < 4; ++rr) {
        int am = m0 + r0 + 32 * rr;
        int tt = am / 28; aow[rr] = am - tt * 28; an[rr] = tt / 28; aoh[rr] = tt - an[rr] * 28;
    }

    // B-staging: thread t stages cols bcol, bcol+32 (2 rounds)
    int bcol = t >> 3;
    int bplog = phys ^ (bcol & 7);                 // (bcol+32)&7 == bcol&7
    const U16* bbase = Bp + (size_t)(co_base + bcol) * KTOT + bplog * 8;

    f32x4 acc[4][2] = {};
    f32x4 acc2[4][2] = {};                         // identity (MODE0 only; DCE'd in MODE3)

    int ks0 = (MODE == 3) ? s * 18 : 0;            // both modes run 18 K-steps of 64

    for (int kq = 0; kq < 18; ++kq) {
        int ks = ks0 + kq;
        int k0 = ks * 64;
        // ---- stage A [128][64] : 4 rounds ----
        if (MODE == 0) {
            int khkw = k0 >> 7, ci0 = k0 & 127;
            int kh = khkw / 3, kw = khkw - 3 * kh;
#pragma unroll
            for (int rr = 0; rr < 4; ++rr) {
                int ih = aoh[rr] * 2 - 1 + kh, iw = aow[rr] * 2 - 1 + kw;
                bool v = ((unsigned)ih < 56) & ((unsigned)iw < 56);
                const U16* sp = v ? Asrc + ((size_t)((an[rr] * 56 + ih) * 56 + iw) << 7) + ci0 + aplog * 8 : zptr;
                gl_lds16(sp, &Ab[(size_t)(rr * 256 + t) * 8]);
            }
        } else {
            int khkw = k0 >> 8, cy0 = k0 & 255;
            int kh = khkw / 3, kw = khkw - 3 * kh;
#pragma unroll
            for (int rr = 0; rr < 4; ++rr) {
                int ih = aoh[rr] - 1 + kh, iw = aow[rr] - 1 + kw;
                bool v = ((unsigned)ih < 28) & ((unsigned)iw < 28);
                const U16* sp = v ? Asrc + ((size_t)((an[rr] * 28 + ih) * 28 + iw) << 8) + cy0 + aplog * 8 : zptr;
                gl_lds16(sp, &Ab[(size_t)(rr * 256 + t) * 8]);
            }
        }
        // ---- stage B [64][64] : 2 rounds ----
#pragma unroll
        for (int r = 0; r < 2; ++r)
            gl_lds16(bbase + (size_t)r * 32 * KTOT + k0, &Bb[(size_t)(r * 256 + t) * 8]);
        __syncthreads();
        // ---- MFMA ----
#pragma unroll
        for (int kk = 0; kk < 2; ++kk) {
            bf16x8 af[4], bfr[2];
#pragma unroll
            for (int i = 0; i < 4; ++i) {
                int row = wr * 64 + i * 16 + (lane & 15);
                int pp = (kk * 4 + (lane >> 4)) ^ (row & 7);
                af[i] = *(const bf16x8*)&Ab[(row * 8 + pp) * 8];
            }
#pragma unroll
            for (int j = 0; j < 2; ++j) {
                int col = wc * 32 + j * 16 + (lane & 15);
                int pp = (kk * 4 + (lane >> 4)) ^ (col & 7);
                bfr[j] = *(const bf16x8*)&Bb[(col * 8 + pp) * 8];
            }
#pragma unroll
            for (int i = 0; i < 4; ++i)
#pragma unroll
                for (int j = 0; j < 2; ++j)
                    acc[i][j] = __builtin_amdgcn_mfma_f32_16x16x32_bf16(af[i], bfr[j], acc[i][j], 0, 0, 0);
            if (MODE == 0 && (ks == 8 || ks == 9)) {   // center tap: fused 1x1 shortcut, B2 via regs
#pragma unroll
                for (int j = 0; j < 2; ++j) {
                    int col = wc * 32 + j * 16 + (lane & 15);
                    int q = kk * 4 + (lane >> 4);
                    bf16x8 b2v = *(const bf16x8*)&B2p[(size_t)(co_base + col) * 128 + (ks - 8) * 64 + q * 8];
#pragma unroll
                    for (int i = 0; i < 4; ++i)
                        acc2[i][j] = __builtin_amdgcn_mfma_f32_16x16x32_bf16(af[i], b2v, acc2[i][j], 0, 0, 0);
                }
            }
        }
        __syncthreads();
    }

    // ---- epilogue ----
    float scale = (MODE == 0) ? wsf[SCALE_IDX] : 0.f;
#pragma unroll
    for (int i = 0; i < 4; ++i)
#pragma unroll
        for (int j = 0; j < 2; ++j)
#pragma unroll
            for (int r = 0; r < 4; ++r) {
                int row = wr * 64 + i * 16 + ((lane >> 4) << 2) + r;
                int coll = wc * 32 + j * 16 + (lane & 15);
                float v = acc[i][j][r];
                int m = m0 + row;
                int ow = m % 28, tt2 = m / 28;
                int oh = tt2 % 28, n = tt2 / 28;
                int co = co_base + coll;
                size_t oidx = ((size_t)(n * 256 + co) * 28 + oh) * 28 + ow;
                if (MODE == 0) {
                    float dist = psq_s[row] + wsq_s[coll] - 2.0f * v + EPS_;
                    float y = v * v / dist * scale;
                    ybuf[(size_t)m * 256 + co] = f2bf(y);
                    out[oidx] = acc2[i][j][r];
                } else {
                    ybuf[(size_t)s * OUTSZ + oidx] = f2bf(v);   // ybuf param = partial base (xt region)
                }
            }
}

// ---------------- split-K reduction: out += p0 + p1 (fully coalesced, deterministic) ----------
__global__ void k_red(const U16* __restrict__ p, float* __restrict__ out) {
    int tid = blockIdx.x * 256 + threadIdx.x;      // 802,816 = 3136*256
    size_t base = (size_t)tid * 8;
    uint4 a = *(const uint4*)(p + base);
    uint4 b = *(const uint4*)(p + (size_t)OUTSZ + base);
    float4 o0 = *(float4*)(out + base);
    float4 o1 = *(float4*)(out + base + 4);
    const unsigned* aw = (const unsigned*)&a;
    const unsigned* bw = (const unsigned*)&b;
    float r[8];
#pragma unroll
    for (int w = 0; w < 4; ++w) {
        r[2 * w]     = b2f((U16)(aw[w] & 0xffff)) + b2f((U16)(bw[w] & 0xffff));
        r[2 * w + 1] = b2f((U16)(aw[w] >> 16))    + b2f((U16)(bw[w] >> 16));
    }
    o0.x += r[0]; o0.y += r[1]; o0.z += r[2]; o0.w += r[3];
    o1.x += r[4]; o1.y += r[5]; o1.z += r[6]; o1.w += r[7];
    *(float4*)(out + base)     = o0;
    *(float4*)(out + base + 4) = o1;
}

extern "C" void kernel_launch(void* const* d_in, const int* in_sizes, int n_in,
                              void* d_out, int out_size, void* d_ws, size_t ws_size,
                              hipStream_t stream) {
    const float* x       = (const float*)d_in[0];
    const float* w_yat   = (const float*)d_in[1];
    const float* alpha   = (const float*)d_in[2];
    const float* w_lin   = (const float*)d_in[3];
    const float* w_short = (const float*)d_in[4];
    float* out = (float*)d_out;
    float* wsf = (float*)d_ws;

    U16* xt = (U16*)((char*)d_ws + U16_BYTE_OFF);
    U16* yb = xt + (size_t)N_ * H_ * W_ * CIN;        // 12,845,056 U16
    U16* B1 = yb + (size_t)OUTSZ;                     // +6,422,528
    U16* B2 = B1 + 1152 * COUT;                       // +294,912
    U16* B3 = B2 + CIN * COUT;                        // +32,768   (B3: 589,824)
    // split-K partials alias xt (dead after gemm0): 2 x OUTSZ U16 = 12,845,056 U16 exactly

    k_prep<<<10112, 256, 0, stream>>>(x, w_yat, w_lin, w_short, alpha, xt, B1, B3, B2, wsf);
    k_psq <<<6272,  256, 0, stream>>>(xt, wsf);

    k_gemm<1152, 0><<<784,  256, 0, stream>>>(xt, B1, B2, wsf, yb, out);
    k_gemm<2304, 3><<<1568, 256, 0, stream>>>(yb, B3, nullptr, wsf, xt, nullptr);
    k_red <<<3136, 256, 0, stream>>>(xt, out);
}